// Round 12
// baseline (67.447 us; speedup 1.0000x reference)
//
#include <hip/hip_runtime.h>
#include <hip/hip_bf16.h>
#include <math.h>

// Causal self-attention fwd, B=2 H=16 T=2048 D=64, fp32 in/out.
// Pre-pass: K and V -> bf16 MFMA-fragment-ordered images per 64x64 tile
// (fragment f's lane l at base + f*1024 + l*16 -> 1KB coalesced wave loads).
// Main: 1024 blocks x 256 threads. Block owns the q-tile PAIR {j, 63-j}
// (exactly 33 k-tiles total for every j); wave w takes kt === w (mod 4) ->
// EVERY wave in the grid runs 8-9 iters (no stragglers), 16 live waves/CU.
// 1-deep K-fragment prefetch (A/B register sets); V loads hidden under
// softmax. 4-way partial combine via LDS, deterministic. 32x32x16 MFMA,
// swapped QK^T, bare exp2 softmax (Q pre-scaled by 0.125*log2e), P in
// registers via v_cvt_pk_bf16_f32 + v_permlane32_swap_b32.

#define BATCH 2
#define HEADS 16
#define SEQ   2048
#define DIM   64
#define NBH   (BATCH * HEADS)          // 32
#define NKT_G (SEQ / 64)               // 32 tiles per (b,h)
#define TILE_SHORTS 4096               // 64x64 bf16 tile (8KB)

typedef __attribute__((ext_vector_type(8)))  short    bf16x8;
typedef __attribute__((ext_vector_type(4)))  unsigned u32x4;
typedef __attribute__((ext_vector_type(4)))  float    f32x4;
typedef __attribute__((ext_vector_type(16))) float    f32x16;

__device__ inline short f2bf(float f) {
    unsigned u = __builtin_bit_cast(unsigned, f);
    u += 0x7fff + ((u >> 16) & 1);      // round-to-nearest-even
    return (short)(u >> 16);
}

__device__ inline unsigned cvtpk(float a, float b) {   // low16 = a, high16 = b
    unsigned r;
    asm("v_cvt_pk_bf16_f32 %0, %1, %2" : "=v"(r) : "v"(a), "v"(b));
    return r;
}

// ---- pre-pass: one block per (bh, kt) 64x64 tile ----
// K frag (kb,ds): lane l holds K[kb*32 + (l&31)][ds*16 + (l>>5)*8 + j]
// V frag (db,s):  lane l holds V[s*16 + (l>>5)*8 + j][db*32 + (l&31)]
__global__ __launch_bounds__(256)
void prep_kv(const float* __restrict__ K, const float* __restrict__ V,
             short* __restrict__ Kimg, short* __restrict__ Vimg) {
    const int tile = blockIdx.x;                 // (bh*32 + kt), 0..1023
    const int tid  = threadIdx.x;
    const float* Ksrc = K + (size_t)tile * TILE_SHORTS;
    const float* Vsrc = V + (size_t)tile * TILE_SHORTS;
    char* Kdst = (char*)(Kimg + (size_t)tile * TILE_SHORTS);
    char* Vdst = (char*)(Vimg + (size_t)tile * TILE_SHORTS);

    __shared__ float vt[64][65];

    {   // stage V rows -> LDS fp32 (coalesced reads)
        const int r  = tid >> 2;
        const int c0 = (tid & 3) * 16;
        #pragma unroll
        for (int j = 0; j < 16; j += 4) {
            const f32x4 v = *reinterpret_cast<const f32x4*>(Vsrc + (size_t)r * 64 + c0 + j);
            vt[r][c0+j] = v[0]; vt[r][c0+j+1] = v[1]; vt[r][c0+j+2] = v[2]; vt[r][c0+j+3] = v[3];
        }
    }

    const int f = tid >> 6;                      // 0..3 (ds or s)
    const int l = tid & 63;
    const int l31 = l & 31;
    const int l8  = (l >> 5) * 8;

    #pragma unroll
    for (int kb = 0; kb < 2; ++kb) {
        const float* src = Ksrc + (size_t)(kb * 32 + l31) * 64 + f * 16 + l8;
        const f32x4 a = *reinterpret_cast<const f32x4*>(src);
        const f32x4 b = *reinterpret_cast<const f32x4*>(src + 4);
        short h[8];
        #pragma unroll
        for (int j = 0; j < 4; ++j) { h[j] = f2bf(a[j]); h[4+j] = f2bf(b[j]); }
        *reinterpret_cast<bf16x8*>(Kdst + ((kb * 4 + f) * 64 + l) * 16) =
            *reinterpret_cast<bf16x8*>(h);
    }

    __syncthreads();

    #pragma unroll
    for (int db = 0; db < 2; ++db) {
        const int d  = db * 32 + l31;
        const int k0 = f * 16 + l8;
        short h[8];
        #pragma unroll
        for (int j = 0; j < 8; ++j) h[j] = f2bf(vt[k0 + j][d]);
        *reinterpret_cast<bf16x8*>(Vdst + ((db * 4 + f) * 64 + l) * 16) =
            *reinterpret_cast<bf16x8*>(h);
    }
}

__global__ __launch_bounds__(256)
void fa_fwd(const float* __restrict__ Q, const short* __restrict__ Kimg,
            const short* __restrict__ Vimg, float* __restrict__ O) {
    const int tid  = threadIdx.x;
    const int lane = tid & 63;
    const int w    = tid >> 6;                   // wave 0..3 : kt === w (mod 4)
    const int q31  = lane & 31;
    const int hi2  = lane >> 5;                  // 0,1

    const int idx = blockIdx.x;                  // 0..1023
    const int bh  = idx & 31;                    // XCD-local images
    const int jp  = idx >> 5;                    // pair index 0..31

    const float* Qb = Q + (size_t)bh * SEQ * DIM;
    float*       Ob = O + (size_t)bh * SEQ * DIM;
    const char*  Ktb = (const char*)(Kimg + (size_t)bh * NKT_G * TILE_SHORTS);
    const char*  Vtb = (const char*)(Vimg + (size_t)bh * NKT_G * TILE_SHORTS);
    const unsigned lb = (unsigned)lane * 16;     // lane byte offset in a frag

    __shared__ float accL[3][32][64];            // 24KB partial-O combine
    __shared__ float rsL[3][32];

    const float SCL = 0.18033688011112042f;      // 0.125 * log2(e)

    #pragma unroll 1
    for (int half = 0; half < 2; ++half) {
        const int p    = half ? (63 - jp) : jp;  // 32-row q-tile index
        const int kdc  = p >> 1;                 // diagonal 64-k-tile
        const int qrel = (p & 1) * 32 + q31;     // mask threshold on diag tile
        const int qw   = p * 32;                 // first q row

        // ---- Q B-frags, pre-scaled: col=q=q31, k(d)=hi2*8+j ----
        bf16x8 qf[4];
        #pragma unroll
        for (int ds = 0; ds < 4; ++ds) {
            const float* src = Qb + (size_t)(qw + q31) * DIM + ds * 16 + hi2 * 8;
            const f32x4 a = *reinterpret_cast<const f32x4*>(src);
            const f32x4 b = *reinterpret_cast<const f32x4*>(src + 4);
            bf16x8 q;
            #pragma unroll
            for (int jj = 0; jj < 4; ++jj) {
                q[jj]     = f2bf(a[jj] * SCL);
                q[4 + jj] = f2bf(b[jj] * SCL);
            }
            qf[ds] = q;
        }

        f32x16 acc0 = {}, acc1 = {};             // partial O[32q][d 0-31|32-63]
        float rs = 0.f;

        bf16x8 kfA[2][4], kfB[2][4];

        auto loadK = [&](bf16x8 (&kf)[2][4], int kt) {
            const char* Kt = Ktb + (size_t)kt * 8192;
            #pragma unroll
            for (int kb = 0; kb < 2; ++kb)
                #pragma unroll
                for (int ds = 0; ds < 4; ++ds)
                    kf[kb][ds] = *reinterpret_cast<const bf16x8*>(
                        Kt + (kb * 4 + ds) * 1024 + lb);
        };

        auto compute = [&](bf16x8 (&kf)[2][4], int kt) {
            // V frags issued first; latency hides under QK^T + softmax
            const char* Vt = Vtb + (size_t)kt * 8192;
            bf16x8 vf[2][4];
            #pragma unroll
            for (int db = 0; db < 2; ++db)
                #pragma unroll
                for (int s = 0; s < 4; ++s)
                    vf[db][s] = *reinterpret_cast<const bf16x8*>(
                        Vt + (db * 4 + s) * 1024 + lb);

            f32x16 st0 = {}, st1 = {};
            __builtin_amdgcn_s_setprio(1);
            #pragma unroll
            for (int ds = 0; ds < 4; ++ds)
                st0 = __builtin_amdgcn_mfma_f32_32x32x16_bf16(kf[0][ds], qf[ds], st0, 0, 0, 0);
            #pragma unroll
            for (int ds = 0; ds < 4; ++ds)
                st1 = __builtin_amdgcn_mfma_f32_32x32x16_bf16(kf[1][ds], qf[ds], st1, 0, 0, 0);
            __builtin_amdgcn_s_setprio(0);

            const bool lastt = (kt == kdc);
            float p0[16], p1[16];
            #pragma unroll
            for (int r = 0; r < 16; ++r) {
                const int kloc = (r & 3) + 8 * (r >> 2) + 4 * hi2;
                float v0 = __builtin_amdgcn_exp2f(st0[r]);
                float v1 = __builtin_amdgcn_exp2f(st1[r]);
                if (lastt) {
                    if (kloc > qrel)      v0 = 0.f;
                    if (kloc + 32 > qrel) v1 = 0.f;
                }
                p0[r] = v0; p1[r] = v1;
                rs += v0 + v1;
            }

            __builtin_amdgcn_s_setprio(1);
            #pragma unroll
            for (int s = 0; s < 4; ++s) {
                const float* pk = (s >> 1) ? p1 : p0;
                const int u = (s & 1) * 8;
                unsigned Xa = cvtpk(pk[u],     pk[u + 1]);
                unsigned Ya = cvtpk(pk[u + 2], pk[u + 3]);
                unsigned Xb = cvtpk(pk[u + 4], pk[u + 5]);
                unsigned Yb = cvtpk(pk[u + 6], pk[u + 7]);
                asm("v_permlane32_swap_b32 %0, %1" : "+v"(Xa), "+v"(Xb));
                asm("v_permlane32_swap_b32 %0, %1" : "+v"(Ya), "+v"(Yb));
                const u32x4 ww = {Xa, Ya, Xb, Yb};
                const bf16x8 pa = __builtin_bit_cast(bf16x8, ww);
                acc0 = __builtin_amdgcn_mfma_f32_32x32x16_bf16(pa, vf[0][s], acc0, 0, 0, 0);
                acc1 = __builtin_amdgcn_mfma_f32_32x32x16_bf16(pa, vf[1][s], acc1, 0, 0, 0);
            }
            __builtin_amdgcn_s_setprio(0);
        };

        // ---- k-loop, stride 4, 1-deep K prefetch (A/B named sets) ----
        int kt = w;
        if (kt <= kdc) {
            loadK(kfA, kt);
            while (true) {
                int ktn = kt + 4;
                const bool vB = (ktn <= kdc);
                if (vB) loadK(kfB, ktn);
                compute(kfA, kt);
                if (!vB) break;
                kt = ktn; ktn = kt + 4;
                const bool vA = (ktn <= kdc);
                if (vA) loadK(kfA, ktn);
                compute(kfB, kt);
                if (!vA) break;
                kt = ktn;
            }
        }

        // ---- 4-way deterministic combine via LDS ----
        rs += __shfl_xor(rs, 32, 64);            // both k-halves within wave

        if (w > 0) {
            #pragma unroll
            for (int r = 0; r < 16; ++r) {
                const int off = (r & 3) + 8 * (r >> 2) + 4 * hi2;
                accL[w - 1][off][q31]      = acc0[r];
                accL[w - 1][off][q31 + 32] = acc1[r];
            }
            if (lane < 32) rsL[w - 1][lane] = rs;
        }
        __syncthreads();
        if (w == 0) {
            const float rstot = rs + rsL[0][q31] + rsL[1][q31] + rsL[2][q31];
            const float inv = 1.0f / rstot;
            #pragma unroll
            for (int r = 0; r < 16; ++r) {
                const int off = (r & 3) + 8 * (r >> 2) + 4 * hi2;
                const float ir = __shfl(inv, off, 64);
                const float o0 = acc0[r] + accL[0][off][q31]
                               + accL[1][off][q31] + accL[2][off][q31];
                const float o1 = acc1[r] + accL[0][off][q31 + 32]
                               + accL[1][off][q31 + 32] + accL[2][off][q31 + 32];
                float* dst = Ob + (size_t)(qw + off) * DIM + q31;
                dst[0]  = o0 * ir;
                dst[32] = o1 * ir;
            }
        }
        __syncthreads();                         // LDS reuse by next half
    }
}

extern "C" void kernel_launch(void* const* d_in, const int* in_sizes, int n_in,
                              void* d_out, int out_size, void* d_ws, size_t ws_size,
                              hipStream_t stream) {
    const float* Q = (const float*)d_in[0];
    const float* K = (const float*)d_in[1];
    const float* V = (const float*)d_in[2];
    float*       O = (float*)d_out;

    short* Kimg = (short*)d_ws;                                        // 8 MiB
    short* Vimg = (short*)d_ws + (size_t)NBH * NKT_G * TILE_SHORTS;    // 8 MiB

    prep_kv<<<dim3(NBH * NKT_G), dim3(256), 0, stream>>>(K, V, Kimg, Vimg);
    fa_fwd<<<dim3(NBH * 32), dim3(256), 0, stream>>>(Q, Kimg, Vimg, O);
}

// Round 13
// 54.745 us; speedup vs baseline: 1.2320x; 1.2320x over previous
//
#include <hip/hip_runtime.h>
#include <hip/hip_bf16.h>
#include <math.h>

// Causal self-attention fwd, B=2 H=16 T=2048 D=64, fp32 in/out.
// Pre-pass: K and V -> bf16 MFMA-fragment-ordered images per 64x64 tile
// (fragment f's lane l at base + f*1024 + l*16).
// Main: 512 blocks x 256 threads; block = 128 q-rows (4 waves x 32q) sharing
// each 64-row K-tile. K double-buffered in LDS via global_load_lds (linear
// dest, fragment order preserved -> conflict-free b128 reads); V loaded
// DIRECT from the L2-resident image (coalesced 1KB fragment loads) so K and
// V travel on different pipes (LDS vs TA/L1). P never touches memory:
// v_cvt_pk_bf16_f32 + v_permlane32_swap_b32. 32x32x16 MFMA, swapped QK^T,
// bare exp2 softmax (Q pre-scaled by 0.125*log2e). Per-wave epilogue.
// qt pairing (jj, 23-jj) gives every CU-pair exactly 34 block-tiles.

#define BATCH 2
#define HEADS 16
#define SEQ   2048
#define DIM   64
#define NBH   (BATCH * HEADS)          // 32
#define NKT_G (SEQ / 64)               // 32 tiles per (b,h)
#define TILE_SHORTS 4096               // 64x64 bf16 tile (8KB)

typedef __attribute__((ext_vector_type(8)))  short    bf16x8;
typedef __attribute__((ext_vector_type(4)))  unsigned u32x4;
typedef __attribute__((ext_vector_type(4)))  float    f32x4;
typedef __attribute__((ext_vector_type(16))) float    f32x16;

__device__ inline short f2bf(float f) {
    unsigned u = __builtin_bit_cast(unsigned, f);
    u += 0x7fff + ((u >> 16) & 1);      // round-to-nearest-even
    return (short)(u >> 16);
}

__device__ inline unsigned cvtpk(float a, float b) {   // low16 = a, high16 = b
    unsigned r;
    asm("v_cvt_pk_bf16_f32 %0, %1, %2" : "=v"(r) : "v"(a), "v"(b));
    return r;
}

__device__ inline void gload16(const void* g, void* l) {
    __builtin_amdgcn_global_load_lds(
        (const __attribute__((address_space(1))) unsigned*)g,
        (__attribute__((address_space(3))) unsigned*)l, 16, 0, 0);
}

// ---- pre-pass: one block per (bh, kt) 64x64 tile ----
// K frag (kb,ds): lane l holds K[kb*32 + (l&31)][ds*16 + (l>>5)*8 + j]
// V frag (db,s):  lane l holds V[s*16 + (l>>5)*8 + j][db*32 + (l&31)]
__global__ __launch_bounds__(256)
void prep_kv(const float* __restrict__ K, const float* __restrict__ V,
             short* __restrict__ Kimg, short* __restrict__ Vimg) {
    const int tile = blockIdx.x;                 // (bh*32 + kt), 0..1023
    const int tid  = threadIdx.x;
    const float* Ksrc = K + (size_t)tile * TILE_SHORTS;
    const float* Vsrc = V + (size_t)tile * TILE_SHORTS;
    char* Kdst = (char*)(Kimg + (size_t)tile * TILE_SHORTS);
    char* Vdst = (char*)(Vimg + (size_t)tile * TILE_SHORTS);

    __shared__ float vt[64][65];

    {   // stage V rows -> LDS fp32 (coalesced reads)
        const int r  = tid >> 2;
        const int c0 = (tid & 3) * 16;
        #pragma unroll
        for (int j = 0; j < 16; j += 4) {
            const f32x4 v = *reinterpret_cast<const f32x4*>(Vsrc + (size_t)r * 64 + c0 + j);
            vt[r][c0+j] = v[0]; vt[r][c0+j+1] = v[1]; vt[r][c0+j+2] = v[2]; vt[r][c0+j+3] = v[3];
        }
    }

    const int f = tid >> 6;                      // 0..3 (ds or s)
    const int l = tid & 63;
    const int l31 = l & 31;
    const int l8  = (l >> 5) * 8;

    #pragma unroll
    for (int kb = 0; kb < 2; ++kb) {
        const float* src = Ksrc + (size_t)(kb * 32 + l31) * 64 + f * 16 + l8;
        const f32x4 a = *reinterpret_cast<const f32x4*>(src);
        const f32x4 b = *reinterpret_cast<const f32x4*>(src + 4);
        short h[8];
        #pragma unroll
        for (int j = 0; j < 4; ++j) { h[j] = f2bf(a[j]); h[4+j] = f2bf(b[j]); }
        *reinterpret_cast<bf16x8*>(Kdst + ((kb * 4 + f) * 64 + l) * 16) =
            *reinterpret_cast<bf16x8*>(h);
    }

    __syncthreads();

    #pragma unroll
    for (int db = 0; db < 2; ++db) {
        const int d  = db * 32 + l31;
        const int k0 = f * 16 + l8;
        short h[8];
        #pragma unroll
        for (int j = 0; j < 8; ++j) h[j] = f2bf(vt[k0 + j][d]);
        *reinterpret_cast<bf16x8*>(Vdst + ((db * 4 + f) * 64 + l) * 16) =
            *reinterpret_cast<bf16x8*>(h);
    }
}

__global__ __launch_bounds__(256)
void fa_fwd(const float* __restrict__ Q, const short* __restrict__ Kimg,
            const short* __restrict__ Vimg, float* __restrict__ O) {
    const int tid  = threadIdx.x;
    const int lane = tid & 63;
    const int w    = tid >> 6;                   // wave 0..3 -> q sub-tile
    const int q31  = lane & 31;
    const int hi2  = lane >> 5;                  // 0,1

    const int idx = blockIdx.x;                  // 0..511
    const int bh  = idx & 31;                    // XCD-local images
    const int jj  = idx >> 5;                    // 0..15
    const int qt  = (jj < 8) ? jj : (23 - jj);   // CU pair sums to 15
    const int q0  = qt * 128;
    const int qw  = q0 + w * 32;                 // wave's first q row
    const int nkt = 2 * qt + 2;                  // block's k-tiles
    const int kd  = 2 * qt + (w >> 1);           // wave's diagonal k-tile
    const int qrel = (w & 1) * 32 + q31;         // mask threshold on diag tile

    const float* Qb = Q + (size_t)bh * SEQ * DIM;
    float*       Ob = O + (size_t)bh * SEQ * DIM;
    const char*  Ktb = (const char*)(Kimg + (size_t)bh * NKT_G * TILE_SHORTS);
    const char*  Vtb = (const char*)(Vimg + (size_t)bh * NKT_G * TILE_SHORTS);
    const unsigned lb = (unsigned)lane * 16;     // lane byte offset in a frag

    __shared__ short Klds[2][TILE_SHORTS];       // 16 KB, double-buffered K

    // stage K tile kt into buffer bb: linear copy, fragment order preserved.
    // LDS dest must be wave-uniform base (HW adds lane*16).
    auto stage = [&](int bb, int kt) {
        const char* Kt = Ktb + (size_t)kt * 8192;
        char* Lb = (char*)Klds[bb] + (unsigned)w * 1024;
        gload16(Kt + (unsigned)w * 1024 + lb,        Lb);
        gload16(Kt + 4096 + (unsigned)w * 1024 + lb, (char*)Lb + 4096);
    };

    // ---- Q B-frags, pre-scaled by 0.125*log2(e): col=q=q31, k(d)=hi2*8+j ----
    const float SCL = 0.18033688011112042f;
    bf16x8 qf[4];
    #pragma unroll
    for (int ds = 0; ds < 4; ++ds) {
        const float* src = Qb + (size_t)(qw + q31) * DIM + ds * 16 + hi2 * 8;
        const f32x4 a = *reinterpret_cast<const f32x4*>(src);
        const f32x4 b = *reinterpret_cast<const f32x4*>(src + 4);
        bf16x8 q;
        #pragma unroll
        for (int jx = 0; jx < 4; ++jx) {
            q[jx]     = f2bf(a[jx] * SCL);
            q[4 + jx] = f2bf(b[jx] * SCL);
        }
        qf[ds] = q;
    }

    f32x16 acc0 = {}, acc1 = {};                 // O[32q][d 0-31 | 32-63]
    float rs = 0.f;

    stage(0, 0);
    __syncthreads();

    for (int kt = 0; kt < nkt; ++kt) {
        const int bb = kt & 1;
        if (kt + 1 < nkt) stage(bb ^ 1, kt + 1);

        if (kt <= kd) {
            // ---- V frags direct from L2 image (TA pipe), issued early ----
            const char* Vt = Vtb + (size_t)kt * 8192;
            bf16x8 vf[2][4];
            #pragma unroll
            for (int db = 0; db < 2; ++db)
                #pragma unroll
                for (int s = 0; s < 4; ++s)
                    vf[db][s] = *reinterpret_cast<const bf16x8*>(
                        Vt + (db * 4 + s) * 1024 + lb);

            // ---- K frags from LDS (LDS pipe) ----
            const char* Kb = (const char*)Klds[bb];
            bf16x8 kf[2][4];
            #pragma unroll
            for (int kb = 0; kb < 2; ++kb)
                #pragma unroll
                for (int ds = 0; ds < 4; ++ds)
                    kf[kb][ds] = *reinterpret_cast<const bf16x8*>(
                        Kb + (kb * 4 + ds) * 1024 + lb);

            // ---- S^T = K Q^T ----
            f32x16 st0 = {}, st1 = {};
            __builtin_amdgcn_s_setprio(1);
            #pragma unroll
            for (int ds = 0; ds < 4; ++ds)
                st0 = __builtin_amdgcn_mfma_f32_32x32x16_bf16(kf[0][ds], qf[ds], st0, 0, 0, 0);
            #pragma unroll
            for (int ds = 0; ds < 4; ++ds)
                st1 = __builtin_amdgcn_mfma_f32_32x32x16_bf16(kf[1][ds], qf[ds], st1, 0, 0, 0);
            __builtin_amdgcn_s_setprio(0);

            // ---- bare-exp2 softmax; mask only on the wave's diagonal tile ----
            const bool lastt = (kt == kd);
            float p0[16], p1[16];
            #pragma unroll
            for (int r = 0; r < 16; ++r) {
                const int kloc = (r & 3) + 8 * (r >> 2) + 4 * hi2;
                float v0 = __builtin_amdgcn_exp2f(st0[r]);
                float v1 = __builtin_amdgcn_exp2f(st1[r]);
                if (lastt) {
                    if (kloc > qrel)      v0 = 0.f;
                    if (kloc + 32 > qrel) v1 = 0.f;
                }
                p0[r] = v0; p1[r] = v1;
                rs += v0 + v1;
            }

            // ---- P -> bf16 A-frags in-register (cvt_pk + permlane32_swap) ----
            __builtin_amdgcn_s_setprio(1);
            #pragma unroll
            for (int s = 0; s < 4; ++s) {
                const float* pk = (s >> 1) ? p1 : p0;
                const int u = (s & 1) * 8;
                unsigned Xa = cvtpk(pk[u],     pk[u + 1]);
                unsigned Ya = cvtpk(pk[u + 2], pk[u + 3]);
                unsigned Xb = cvtpk(pk[u + 4], pk[u + 5]);
                unsigned Yb = cvtpk(pk[u + 6], pk[u + 7]);
                asm("v_permlane32_swap_b32 %0, %1" : "+v"(Xa), "+v"(Xb));
                asm("v_permlane32_swap_b32 %0, %1" : "+v"(Ya), "+v"(Yb));
                const u32x4 ww = {Xa, Ya, Xb, Yb};
                const bf16x8 pa = __builtin_bit_cast(bf16x8, ww);
                acc0 = __builtin_amdgcn_mfma_f32_32x32x16_bf16(pa, vf[0][s], acc0, 0, 0, 0);
                acc1 = __builtin_amdgcn_mfma_f32_32x32x16_bf16(pa, vf[1][s], acc1, 0, 0, 0);
            }
            __builtin_amdgcn_s_setprio(0);
        }

        __syncthreads();   // buffer bb consumed; bb^1 staged (vmcnt drained)
    }

    // ---- epilogue: rowsum finish + normalize + store (per wave) ----
    rs += __shfl_xor(rs, 32, 64);                // both k-halves -> full row sum
    const float inv = 1.0f / rs;                 // valid for q = q31 on both halves
    #pragma unroll
    for (int r = 0; r < 16; ++r) {
        const int off = (r & 3) + 8 * (r >> 2) + 4 * hi2;
        const float ir = __shfl(inv, off, 64);
        float* dst = Ob + (size_t)(qw + off) * DIM + q31;
        dst[0]  = acc0[r] * ir;
        dst[32] = acc1[r] * ir;
    }
}

extern "C" void kernel_launch(void* const* d_in, const int* in_sizes, int n_in,
                              void* d_out, int out_size, void* d_ws, size_t ws_size,
                              hipStream_t stream) {
    const float* Q = (const float*)d_in[0];
    const float* K = (const float*)d_in[1];
    const float* V = (const float*)d_in[2];
    float*       O = (float*)d_out;

    short* Kimg = (short*)d_ws;                                        // 8 MiB
    short* Vimg = (short*)d_ws + (size_t)NBH * NKT_G * TILE_SHORTS;    // 8 MiB

    prep_kv<<<dim3(NBH * NKT_G), dim3(256), 0, stream>>>(K, V, Kimg, Vimg);
    fa_fwd<<<dim3(NBH * 16), dim3(256), 0, stream>>>(Q, Kimg, Vimg, O);
}

// Round 14
// 49.459 us; speedup vs baseline: 1.3637x; 1.1069x over previous
//
#include <hip/hip_runtime.h>
#include <hip/hip_bf16.h>
#include <math.h>

// Causal self-attention fwd, B=2 H=16 T=2048 D=64, fp32 in/out.
// = R6 structure (best proven) with V moved OFF the LDS pipe:
// Pre-pass: K -> bf16 swizzled row-major 64x64 tiles (for global_load_lds
// staging + conflict-free ds_read_b128); V -> bf16 16x16-B-FRAG-ORDERED
// image (8 x 1KB fragments; lane l of frag (ks,t) holds
// V[ks*32+(l>>4)*8+j][t*16+(l&15)]) -> direct coalesced 1KB register loads.
// Main: block = 64 q-rows (4 waves x 16), grid 1024 (4 blocks/CU, 24KB LDS,
// 16 waves/CU), heavy-first. K double-buffered in LDS; V direct from L1/L2
// (different pipe, loaded early so latency hides under QK^T+softmax).
// Swapped QK^T, bare exp2 softmax (Q pre-scaled by 0.125*log2e), P via
// small LDS buffer (cvt_pk b64 writes, b128 reads), epilogue-only reduce.

#define BATCH 2
#define HEADS 16
#define SEQ   2048
#define DIM   64
#define QTILE 64
#define KTILE 64
#define NBH   (BATCH * HEADS)          // 32
#define NQT   (SEQ / QTILE)            // 32
#define NKT_G (SEQ / KTILE)            // 32
#define TILE_SHORTS 4096               // 64x64 bf16 tile

typedef __attribute__((ext_vector_type(8))) short bf16x8;
typedef __attribute__((ext_vector_type(4))) short s16x4;
typedef __attribute__((ext_vector_type(2))) unsigned u32x2;
typedef __attribute__((ext_vector_type(4))) float f32x4;

__device__ inline short f2bf(float f) {
    unsigned u = __builtin_bit_cast(unsigned, f);
    u += 0x7fff + ((u >> 16) & 1);      // round-to-nearest-even
    return (short)(u >> 16);
}

__device__ inline unsigned cvtpk(float a, float b) {   // low16 = a, high16 = b
    unsigned r;
    asm("v_cvt_pk_bf16_f32 %0, %1, %2" : "=v"(r) : "v"(a), "v"(b));
    return r;
}

__device__ inline void gload16(const void* g, void* l) {
    __builtin_amdgcn_global_load_lds(
        (const __attribute__((address_space(1))) unsigned*)g,
        (__attribute__((address_space(3))) unsigned*)l, 16, 0, 0);
}

// ---- pre-pass: one block per (bh, kt) tile; K swizzled, V frag-image ----
__global__ __launch_bounds__(256)
void prep_kv(const float* __restrict__ K, const float* __restrict__ V,
             short* __restrict__ Kswz, short* __restrict__ Vimg) {
    const int tile = blockIdx.x;                 // (bh*32 + kt), 0..1023
    const int tid  = threadIdx.x;
    const float* Ksrc = K + (size_t)tile * TILE_SHORTS;
    const float* Vsrc = V + (size_t)tile * TILE_SHORTS;
    char* Kdst = (char*)(Kswz + (size_t)tile * TILE_SHORTS);
    char* Vdst = (char*)(Vimg + (size_t)tile * TILE_SHORTS);

    __shared__ float vt[64][65];

    const int r  = tid >> 2;
    const int c0 = (tid & 3) * 16;

    {   // K[k][d], swizzled 16B slots within 128B rows
        short kh[16];
        #pragma unroll
        for (int j = 0; j < 16; j += 4) {
            const f32x4 v = *reinterpret_cast<const f32x4*>(Ksrc + (size_t)r * 64 + c0 + j);
            kh[j] = f2bf(v[0]); kh[j+1] = f2bf(v[1]); kh[j+2] = f2bf(v[2]); kh[j+3] = f2bf(v[3]);
        }
        const unsigned swz  = ((unsigned)r & 7) << 4;
        const unsigned base = (unsigned)r * 128 + (unsigned)c0 * 2;
        *reinterpret_cast<bf16x8*>(Kdst + (base ^ swz))        = *reinterpret_cast<bf16x8*>(&kh[0]);
        *reinterpret_cast<bf16x8*>(Kdst + ((base + 16) ^ swz)) = *reinterpret_cast<bf16x8*>(&kh[8]);
    }

    #pragma unroll
    for (int j = 0; j < 16; j += 4) {
        const f32x4 v = *reinterpret_cast<const f32x4*>(Vsrc + (size_t)r * 64 + c0 + j);
        vt[r][c0+j] = v[0]; vt[r][c0+j+1] = v[1]; vt[r][c0+j+2] = v[2]; vt[r][c0+j+3] = v[3];
    }
    __syncthreads();

    // V 16x16-B-frag image: slot = fi*64 + l; lane l of frag fi=(ks*4+t)
    // holds V[ks*32 + (l>>4)*8 + j][t*16 + (l&15)], 16B contiguous.
    #pragma unroll
    for (int s2 = 0; s2 < 2; ++s2) {
        const int slot = tid + s2 * 256;         // 0..511
        const int fi = slot >> 6;
        const int l  = slot & 63;
        const int t  = fi & 3;
        const int ks = fi >> 2;
        const int d  = t * 16 + (l & 15);
        const int k0 = ks * 32 + (l >> 4) * 8;
        short h[8];
        #pragma unroll
        for (int j = 0; j < 8; ++j) h[j] = f2bf(vt[k0 + j][d]);
        *reinterpret_cast<bf16x8*>(Vdst + slot * 16) = *reinterpret_cast<bf16x8*>(h);
    }
}

__global__ __launch_bounds__(256)
void fa_fwd(const float* __restrict__ Q, const short* __restrict__ Kswz,
            const short* __restrict__ Vimg, float* __restrict__ O) {
    const int tid  = threadIdx.x;
    const int lane = tid & 63;
    const int wid  = tid >> 6;
    const int lo   = lane & 15;
    const int hi   = lane >> 4;

    // heavy-first balanced mapping; bh = idx&31 -> XCD-local images
    const int idx = blockIdx.x;                 // 0..1023
    const int j   = idx >> 5;                   // 0..31
    const int bh  = idx & 31;
    const int qt  = (j < 16) ? (31 - j) : (j - 16);
    const int q0  = qt * QTILE;

    const float* Qb = Q + (size_t)bh * SEQ * DIM;
    float*       Ob = O + (size_t)bh * SEQ * DIM;
    const size_t tbase = (size_t)bh * NKT_G * TILE_SHORTS;

    __shared__ short Klds[2][TILE_SHORTS];      // 16 KB, double-buffered K
    __shared__ char  Plds[4][2048];             // 8 KB: per-wave 16q x 64k bf16

    const int nkt = qt + 1;

    auto stage = [&](int bb, int kt) {
        const short* Kt = Kswz + tbase + (size_t)kt * TILE_SHORTS;
        const int off = wid * 512 + lane * 8;
        gload16(Kt + off,        &Klds[bb][wid * 512]);
        gload16(Kt + 2048 + off, &Klds[bb][2048 + wid * 512]);
    };

    stage(0, 0);

    // ---- precomputed lane-constant LDS byte offsets ----
    const unsigned swz = ((unsigned)(lo & 7)) << 4;
    const unsigned inner0 = ((unsigned)(lo * 128 + 0 * 64 + hi * 16)) ^ swz;
    const unsigned inner1 = ((unsigned)(lo * 128 + 1 * 64 + hi * 16)) ^ swz;
    const unsigned pbase = (unsigned)wid * 2048;
    unsigned pwr[4];
    #pragma unroll
    for (int t = 0; t < 4; ++t)
        pwr[t] = pbase + (((unsigned)(lo * 128 + t * 32 + hi * 8)) ^ swz);
    const unsigned prd0 = pbase + inner0;
    const unsigned prd1 = pbase + inner1;
    char* const P0 = (char*)Plds;

    // ---- Q fragments, PRE-SCALED by 0.125*log2(e) (B-operand, col=q=lo) ----
    const float SCL = 0.18033688011112042f;
    bf16x8 qf[2];
    {
        const int qrow = q0 + wid * 16 + lo;
        #pragma unroll
        for (int ks = 0; ks < 2; ++ks) {
            const float* src = Qb + (size_t)qrow * DIM + ks * 32 + hi * 8;
            const f32x4 a = *reinterpret_cast<const f32x4*>(src);
            const f32x4 b = *reinterpret_cast<const f32x4*>(src + 4);
            bf16x8 q;
            #pragma unroll
            for (int jj = 0; jj < 4; ++jj) {
                q[jj]     = f2bf(a[jj] * SCL);
                q[4 + jj] = f2bf(b[jj] * SCL);
            }
            qf[ks] = q;
        }
    }

    f32x4 oacc[4] = {};
    float rsum = 0.f;
    const int qg = q0 + wid * 16 + lo;           // this lane's q row (softmax layout)
    const unsigned lb = (unsigned)lane * 16;     // V-frag lane byte offset

    __syncthreads();

    for (int kt = 0; kt < nkt; ++kt) {
        const int bb = kt & 1;
        if (kt + 1 < nkt) stage(bb ^ 1, kt + 1);

        // ---- V frags direct from image (TA/L1 pipe), issued EARLY ----
        const char* Vt = (const char*)(Vimg + tbase + (size_t)kt * TILE_SHORTS);
        bf16x8 vf[2][4];
        #pragma unroll
        for (int ks = 0; ks < 2; ++ks)
            #pragma unroll
            for (int t = 0; t < 4; ++t)
                vf[ks][t] = *reinterpret_cast<const bf16x8*>(
                    Vt + (ks * 4 + t) * 1024 + lb);

        const char* Kb = (const char*)Klds[bb];

        // ---- S^T = K Q^T : rows k, cols q (scores pre-scaled) ----
        f32x4 st[4];
        __builtin_amdgcn_s_setprio(1);
        #pragma unroll
        for (int t = 0; t < 4; ++t) {
            const bf16x8 kf0 = *reinterpret_cast<const bf16x8*>(Kb + inner0 + t * 2048);
            const bf16x8 kf1 = *reinterpret_cast<const bf16x8*>(Kb + inner1 + t * 2048);
            f32x4 acc = {};
            acc = __builtin_amdgcn_mfma_f32_16x16x32_bf16(kf0, qf[0], acc, 0, 0, 0);
            acc = __builtin_amdgcn_mfma_f32_16x16x32_bf16(kf1, qf[1], acc, 0, 0, 0);
            st[t] = acc;
        }
        __builtin_amdgcn_s_setprio(0);

        // ---- bare-exp2 softmax; P k-contiguous per lane -> b64 writes ----
        const bool domask = (kt == nkt - 1);     // only the diagonal tile masks
        {
            float racc0 = 0.f, racc1 = 0.f;
            #pragma unroll
            for (int t = 0; t < 4; ++t) {
                float p[4];
                #pragma unroll
                for (int r = 0; r < 4; ++r) {
                    float arg = st[t][r];
                    if (domask) {
                        const int kg = kt * KTILE + t * 16 + hi * 4 + r;
                        if (kg > qg) arg = -1e30f;
                    }
                    p[r] = __builtin_amdgcn_exp2f(arg);
                }
                racc0 += p[0] + p[1];
                racc1 += p[2] + p[3];
                const u32x2 w = { cvtpk(p[0], p[1]), cvtpk(p[2], p[3]) };
                *reinterpret_cast<s16x4*>(P0 + pwr[t]) = __builtin_bit_cast(s16x4, w);
            }
            rsum += racc0 + racc1;
        }
        asm volatile("" ::: "memory");           // P writes ordered before P reads

        // ---- O += P V  (V from registers, P from LDS) ----
        __builtin_amdgcn_s_setprio(1);
        {
            const bf16x8 pa0 = *reinterpret_cast<const bf16x8*>(P0 + prd0);
            const bf16x8 pa1 = *reinterpret_cast<const bf16x8*>(P0 + prd1);
            #pragma unroll
            for (int t = 0; t < 4; ++t) {
                oacc[t] = __builtin_amdgcn_mfma_f32_16x16x32_bf16(pa0, vf[0][t], oacc[t], 0, 0, 0);
                oacc[t] = __builtin_amdgcn_mfma_f32_16x16x32_bf16(pa1, vf[1][t], oacc[t], 0, 0, 0);
            }
        }
        __builtin_amdgcn_s_setprio(0);

        __syncthreads();
    }

    // ---- epilogue: reduce lane-partial row sums, gather per-output-row ----
    {
        float rs = rsum;
        rs += __shfl_xor(rs, 16, 64);
        rs += __shfl_xor(rs, 32, 64);            // all hi-groups: sum for q=lo
        const float vinv = 1.0f / rs;
        #pragma unroll
        for (int r = 0; r < 4; ++r) {
            const float inv_r = __shfl(vinv, hi * 4 + r, 64);   // row q=hi*4+r
            const int q_idx = q0 + wid * 16 + hi * 4 + r;
            #pragma unroll
            for (int t = 0; t < 4; ++t)
                Ob[(size_t)q_idx * DIM + t * 16 + lo] = oacc[t][r] * inv_r;
        }
    }
}

extern "C" void kernel_launch(void* const* d_in, const int* in_sizes, int n_in,
                              void* d_out, int out_size, void* d_ws, size_t ws_size,
                              hipStream_t stream) {
    const float* Q = (const float*)d_in[0];
    const float* K = (const float*)d_in[1];
    const float* V = (const float*)d_in[2];
    float*       O = (float*)d_out;

    short* Kswz = (short*)d_ws;                                        // 8 MiB
    short* Vimg = (short*)d_ws + (size_t)NBH * NKT_G * TILE_SHORTS;    // 8 MiB

    prep_kv<<<dim3(NBH * NKT_G), dim3(256), 0, stream>>>(K, V, Kswz, Vimg);
    fa_fwd<<<dim3(NBH * NQT), dim3(256), 0, stream>>>(Q, Kswz, Vimg, O);
}